// Round 10
// baseline (348.854 us; speedup 1.0000x reference)
//
#include <hip/hip_runtime.h>
#include <hip/hip_bf16.h>
#include <cstdint>
#include <cstddef>

typedef __bf16 bf16_t;
typedef __bf16 bf16x4 __attribute__((ext_vector_type(4)));
typedef __bf16 bf16x8 __attribute__((ext_vector_type(8)));
typedef float f32x4 __attribute__((ext_vector_type(4)));
typedef float f32x16 __attribute__((ext_vector_type(16)));
typedef float f32x2 __attribute__((ext_vector_type(2)));
typedef int i32x4 __attribute__((ext_vector_type(4)));
typedef int i32x8 __attribute__((ext_vector_type(8)));

#define NROWS 8192
#define DFEAT 1024
#define BK 32
#define NBLK 64            // NROWS/128
#define TILE_B (128 * BK)  // bf16 elems per staged tile (8 KB)
#define F8TILE 8192        // fp8 bytes per staged 128x64 tile
#define NTRI (NBLK * (NBLK + 1) / 2)  // 2080 triangular tiles

typedef __attribute__((address_space(3))) unsigned int lds_uint;
typedef __attribute__((address_space(1))) const unsigned int glb_uint;

__device__ __forceinline__ float fast_tanh(float x) {
  float e = __expf(2.0f * x);
  return 1.0f - 2.0f * __builtin_amdgcn_rcpf(e + 1.0f);
}

// pack 4 floats -> 4 fp8 e4m3 bytes (OCP, HW cvt)
__device__ __forceinline__ unsigned pack_fp8x4(float a, float b, float c, float d) {
  unsigned v = 0;
  v = __builtin_amdgcn_cvt_pk_fp8_f32(a, b, v, false);
  v = __builtin_amdgcn_cvt_pk_fp8_f32(c, d, v, true);
  return v;
}

__global__ __launch_bounds__(256) void cast_kernel(const float* __restrict__ in,
                                                   bf16_t* __restrict__ out, int n4) {
  int i = blockIdx.x * 256 + threadIdx.x;
  if (i < n4) {
    float4 v = *(const float4*)(in + i * 4);
    bf16x4 o = {(bf16_t)v.x, (bf16_t)v.y, (bf16_t)v.z, (bf16_t)v.w};
    *(bf16x4*)(out + i * 4) = o;
  }
}

// Async-stage a 128x32 bf16 tile into contiguous LDS [128][32] via global_load_lds w16.
__device__ __forceinline__ void stage_async(const bf16_t* __restrict__ g, int ld,
                                            int row0, int k0, bf16_t* lds,
                                            int wave, int lane) {
#pragma unroll
  for (int t = 0; t < 2; ++t) {
    const int rb = (t * 4 + wave) * 16;
    const bf16_t* gp = g + (size_t)(row0 + rb + (lane >> 2)) * ld + (k0 + (lane & 3) * 8);
    __builtin_amdgcn_global_load_lds((glb_uint*)gp, (lds_uint*)(lds + rb * BK), 16, 0, 0);
  }
}

// Async-stage a 128x64 fp8 tile into contiguous LDS [128][64B] (row stride 64B).
__device__ __forceinline__ void stage_f8(const uint8_t* __restrict__ g, int ld,
                                         int row0, int k0, uint8_t* lds,
                                         int wave, int lane) {
#pragma unroll
  for (int t = 0; t < 2; ++t) {
    const int rb = (t * 4 + wave) * 16;
    const uint8_t* gp = g + (size_t)(row0 + rb + (lane >> 2)) * ld + (k0 + (lane & 3) * 16);
    __builtin_amdgcn_global_load_lds((glb_uint*)gp, (lds_uint*)(lds + rb * 64), 16, 0, 0);
  }
}

// h = x @ W^T + b, bf16, double-buffered; writes h (bf16, for scores) AND
// hT (fp8 e4m3, consumed only by the MX-fp8 pv kernel).
__global__ __launch_bounds__(256) void gemm1_kernel(const bf16_t* __restrict__ xb,
                                                    const bf16_t* __restrict__ Wb,
                                                    const float* __restrict__ bias,
                                                    bf16_t* __restrict__ hout,
                                                    uint8_t* __restrict__ hT8) {
  __shared__ __align__(16) bf16_t smem[4 * TILE_B];
  const int tid = threadIdx.x;
  const int wave = tid >> 6, lane = tid & 63;
  const int wm = wave >> 1, wn = wave & 1;
  const int l15 = lane & 15, quad = lane >> 4;
  const int m0 = blockIdx.x * 128, n0 = blockIdx.y * 128;
  f32x4 acc[4][4] = {};
  const int NIT = DFEAT / BK;
  stage_async(xb, DFEAT, m0, 0, smem, wave, lane);
  stage_async(Wb, DFEAT, n0, 0, smem + TILE_B, wave, lane);
  __syncthreads();
  for (int it = 0; it < NIT; ++it) {
    bf16_t* lA = smem + (it & 1) * 2 * TILE_B;
    bf16_t* lB = lA + TILE_B;
    if (it + 1 < NIT) {
      bf16_t* nA = smem + ((it + 1) & 1) * 2 * TILE_B;
      stage_async(xb, DFEAT, m0, (it + 1) * BK, nA, wave, lane);
      stage_async(Wb, DFEAT, n0, (it + 1) * BK, nA + TILE_B, wave, lane);
    }
    bf16x8 a[4], b[4];
#pragma unroll
    for (int f = 0; f < 4; ++f) {
      a[f] = *(const bf16x8*)(lA + (wm * 64 + f * 16 + l15) * BK + quad * 8);
      b[f] = *(const bf16x8*)(lB + (wn * 64 + f * 16 + l15) * BK + quad * 8);
    }
#pragma unroll
    for (int i = 0; i < 4; ++i)
#pragma unroll
      for (int j = 0; j < 4; ++j)
        acc[i][j] = __builtin_amdgcn_mfma_f32_16x16x32_bf16(a[i], b[j], acc[i][j], 0, 0, 0);
    __syncthreads();
  }
#pragma unroll
  for (int i = 0; i < 4; ++i) {
    int rbase = m0 + wm * 64 + i * 16 + quad * 4;
#pragma unroll
    for (int j = 0; j < 4; ++j) {
      int col = n0 + wn * 64 + j * 16 + l15;
      float bv = bias[col];
      float hv[4];
#pragma unroll
      for (int r = 0; r < 4; ++r) hv[r] = acc[i][j][r] + bv;
#pragma unroll
      for (int r = 0; r < 4; ++r)
        hout[(size_t)(rbase + r) * DFEAT + col] = (bf16_t)hv[r];
      *(unsigned*)(hT8 + (size_t)col * NROWS + rbase) =
          pack_fp8x4(hv[0], hv[1], hv[2], hv[3]);  // fused transpose, fp8
    }
  }
}

// Symmetric scores, XCD-banded tile ids, pv-pattern DOUBLE-BUFFERED staging
// (stage slice it+1 into alternate 16 KB phase before computing slice it; one
// barrier per iter). Upper-triangular 128x128 tiles of P = exp(tanh(h h^T)),
// fp8 e4m3 out; sums from quantized values.
__global__ __launch_bounds__(256) void scores_sym_kernel(const bf16_t* __restrict__ h,
                                                         uint8_t* __restrict__ P,
                                                         float* __restrict__ lsum) {
  __shared__ __align__(16) char smem[4 * TILE_B * 2];  // 32 KB staging / 18 KB mirror overlay
  uint8_t (*mir)[144] = (uint8_t(*)[144])smem;

  int t = (blockIdx.x & 7) * (NTRI / 8) + (blockIdx.x >> 3);  // XCD banding
  int bm = 0;
  while (t >= NBLK - bm) { t -= NBLK - bm; ++bm; }
  const int bn = bm + t;
  const bool offdiag = (bm != bn);
  const int m0 = bm * 128, n0 = bn * 128;

  const int tid = threadIdx.x;
  const int wave = tid >> 6, lane = tid & 63;
  const int wm = wave >> 1, wn = wave & 1;
  const int l15 = lane & 15, quad = lane >> 4;

  f32x4 acc[4][4] = {};
  const int NIT = DFEAT / BK;
  stage_async(h, DFEAT, m0, 0, (bf16_t*)smem, wave, lane);
  stage_async(h, DFEAT, n0, 0, (bf16_t*)smem + TILE_B, wave, lane);
  __syncthreads();
  for (int it = 0; it < NIT; ++it) {
    bf16_t* lA = (bf16_t*)smem + (it & 1) * 2 * TILE_B;
    bf16_t* lB = lA + TILE_B;
    if (it + 1 < NIT) {
      bf16_t* nA = (bf16_t*)smem + ((it + 1) & 1) * 2 * TILE_B;
      stage_async(h, DFEAT, m0, (it + 1) * BK, nA, wave, lane);
      stage_async(h, DFEAT, n0, (it + 1) * BK, nA + TILE_B, wave, lane);
    }
    bf16x8 a[4], b[4];
#pragma unroll
    for (int f = 0; f < 4; ++f) {
      a[f] = *(const bf16x8*)(lA + (wm * 64 + f * 16 + l15) * BK + quad * 8);
      b[f] = *(const bf16x8*)(lB + (wn * 64 + f * 16 + l15) * BK + quad * 8);
    }
#pragma unroll
    for (int i = 0; i < 4; ++i)
#pragma unroll
      for (int j = 0; j < 4; ++j)
        acc[i][j] = __builtin_amdgcn_mfma_f32_16x16x32_bf16(a[i], b[j], acc[i][j], 0, 0, 0);
    __syncthreads();  // drains next-slice DMA (overlapped with compute) + buffer reuse guard
  }
  // trailing loop barrier guarantees all LDS reads done; smem free for mirror

  float rs[4][4];
  float cs[4];
#pragma unroll
  for (int i = 0; i < 4; ++i)
#pragma unroll
    for (int r = 0; r < 4; ++r) rs[i][r] = 0.f;
#pragma unroll
  for (int j = 0; j < 4; ++j) cs[j] = 0.f;

#pragma unroll
  for (int i = 0; i < 4; ++i) {
    const int rl_loc = wm * 64 + i * 16 + quad * 4;
    const int rbase = m0 + rl_loc;
#pragma unroll
    for (int j = 0; j < 4; ++j) {
      const int cl_loc = wn * 64 + j * 16 + l15;
      const int col = n0 + cl_loc;
      float p[4];
#pragma unroll
      for (int r = 0; r < 4; ++r) p[r] = __expf(fast_tanh(acc[i][j][r]));
      unsigned packed = pack_fp8x4(p[0], p[1], p[2], p[3]);
      // dequantize for sums so the softmax denominator matches stored P
      f32x2 d0 = __builtin_amdgcn_cvt_pk_f32_fp8(packed, false);
      f32x2 d1 = __builtin_amdgcn_cvt_pk_f32_fp8(packed, true);
      float q[4] = {d0.x, d0.y, d1.x, d1.y};
#pragma unroll
      for (int r = 0; r < 4; ++r) {
        rs[i][r] += q[r];
        cs[j] += q[r];
        P[(size_t)(rbase + r) * NROWS + col] = (uint8_t)(packed >> (8 * r));
      }
      if (offdiag) *(unsigned*)&mir[cl_loc][rl_loc] = packed;
    }
  }

#pragma unroll
  for (int off = 1; off < 16; off <<= 1)
#pragma unroll
    for (int i = 0; i < 4; ++i)
#pragma unroll
      for (int r = 0; r < 4; ++r) rs[i][r] += __shfl_xor(rs[i][r], off, 64);
  if (l15 == 0) {
#pragma unroll
    for (int i = 0; i < 4; ++i) {
      int rbase = m0 + wm * 64 + i * 16 + quad * 4;
#pragma unroll
      for (int r = 0; r < 4; ++r) atomicAdd(&lsum[rbase + r], rs[i][r]);
    }
  }

  if (offdiag) {
#pragma unroll
    for (int off = 16; off < 64; off <<= 1)
#pragma unroll
      for (int j = 0; j < 4; ++j) cs[j] += __shfl_xor(cs[j], off, 64);
    if (quad == 0) {
#pragma unroll
      for (int j = 0; j < 4; ++j)
        atomicAdd(&lsum[n0 + wn * 64 + j * 16 + l15], cs[j]);
    }
    __syncthreads();
#pragma unroll
    for (int it = 0; it < 4; ++it) {
      int q = tid + it * 256;          // 0..1023
      int c = q >> 3, r0 = (q & 7) * 16;
      uint4 v = *(const uint4*)(&mir[c][r0]);
      *(uint4*)(P + (size_t)(n0 + c) * NROWS + m0 + r0) = v;
    }
  }
}

// out = tanh((P @ h) / l): MX-fp8 (e4m3) MFMA with unity scales, K=64/iter,
// double-buffered staging. Grid (x=m=64, y=n=8) keeps same-m0 blocks on one
// XCD -> P strip L2-resident.
__global__ __launch_bounds__(256) void pv_kernel(const uint8_t* __restrict__ P,
                                                 const uint8_t* __restrict__ hT8,
                                                 const float* __restrict__ lsum,
                                                 float* __restrict__ out) {
  __shared__ __align__(16) uint8_t smem[4 * F8TILE];  // 2 phases x (A 8KB + B 8KB)
  const int tid = threadIdx.x;
  const int wave = tid >> 6, lane = tid & 63;
  const int wm = wave >> 1, wn = wave & 1;
  const int l31 = lane & 31, khalf = lane >> 5;
  const int m0 = blockIdx.x * 128, n0 = blockIdx.y * 128;
  f32x16 acc[2][2] = {};
  const int NIT = NROWS / 64;
  stage_f8(P, NROWS, m0, 0, smem, wave, lane);
  stage_f8(hT8, NROWS, n0, 0, smem + F8TILE, wave, lane);
  __syncthreads();
  for (int it = 0; it < NIT; ++it) {
    uint8_t* lA = smem + (it & 1) * 2 * F8TILE;
    uint8_t* lB = lA + F8TILE;
    if (it + 1 < NIT) {
      uint8_t* nA = smem + ((it + 1) & 1) * 2 * F8TILE;
      stage_f8(P, NROWS, m0, (it + 1) * 64, nA, wave, lane);
      stage_f8(hT8, NROWS, n0, (it + 1) * 64, nA + F8TILE, wave, lane);
    }
    i32x8 a[2], b[2];
#pragma unroll
    for (int f = 0; f < 2; ++f) {
      {
        int off = (wm * 64 + f * 32 + l31) * 64 + khalf * 32;
        i32x4 lo = *(const i32x4*)(lA + off);
        i32x4 hi = *(const i32x4*)(lA + off + 16);
        a[f] = i32x8{lo[0], lo[1], lo[2], lo[3], hi[0], hi[1], hi[2], hi[3]};
      }
      {
        int off = (wn * 64 + f * 32 + l31) * 64 + khalf * 32;
        i32x4 lo = *(const i32x4*)(lB + off);
        i32x4 hi = *(const i32x4*)(lB + off + 16);
        b[f] = i32x8{lo[0], lo[1], lo[2], lo[3], hi[0], hi[1], hi[2], hi[3]};
      }
    }
#pragma unroll
    for (int bi = 0; bi < 2; ++bi)
#pragma unroll
      for (int bj = 0; bj < 2; ++bj)
        acc[bi][bj] = __builtin_amdgcn_mfma_scale_f32_32x32x64_f8f6f4(
            a[bi], b[bj], acc[bi][bj], 0, 0, 0, 0x7F7F7F7F, 0, 0x7F7F7F7F);
    __syncthreads();
  }
  // C/D 32x32: col = lane&31, row = (reg&3) + 8*(reg>>2) + 4*(lane>>5)
#pragma unroll
  for (int bi = 0; bi < 2; ++bi)
#pragma unroll
    for (int bj = 0; bj < 2; ++bj) {
      int cbase = n0 + wn * 64 + bj * 32 + l31;
#pragma unroll
      for (int reg = 0; reg < 16; ++reg) {
        int row = m0 + wm * 64 + bi * 32 + (reg & 3) + 8 * (reg >> 2) + 4 * khalf;
        float rl = __builtin_amdgcn_rcpf(lsum[row]);
        out[(size_t)row * DFEAT + cbase] = fast_tanh(acc[bi][bj][reg] * rl);
      }
    }
}

extern "C" void kernel_launch(void* const* d_in, const int* in_sizes, int n_in,
                              void* d_out, int out_size, void* d_ws, size_t ws_size,
                              hipStream_t stream) {
  const float* x = (const float*)d_in[0];
  const float* W = (const float*)d_in[1];
  const float* bias = (const float*)d_in[2];
  float* out = (float*)d_out;

  bf16_t* xb = (bf16_t*)d_ws;                        // 16 MB
  bf16_t* Wb = xb + (size_t)NROWS * DFEAT;           // 2 MB
  bf16_t* h  = Wb + (size_t)DFEAT * DFEAT;           // 16 MB
  uint8_t* hT8 = (uint8_t*)(h + (size_t)NROWS * DFEAT);  // 8 MB (fp8)
  float* lsum = (float*)(hT8 + (size_t)DFEAT * NROWS);
  uint8_t* P = (uint8_t*)(lsum + NROWS);             // 67 MB (fp8)

  cast_kernel<<<(NROWS * DFEAT / 4) / 256, 256, 0, stream>>>(x, xb, NROWS * DFEAT / 4);
  cast_kernel<<<(DFEAT * DFEAT / 4) / 256, 256, 0, stream>>>(W, Wb, DFEAT * DFEAT / 4);
  gemm1_kernel<<<dim3(NROWS / 128, DFEAT / 128), 256, 0, stream>>>(xb, Wb, bias, h, hT8);
  hipMemsetAsync(lsum, 0, NROWS * sizeof(float), stream);
  scores_sym_kernel<<<NTRI, 256, 0, stream>>>(h, P, lsum);
  pv_kernel<<<dim3(NROWS / 128, DFEAT / 128), 256, 0, stream>>>(P, hT8, lsum, out);
}

// Round 11
// 324.760 us; speedup vs baseline: 1.0742x; 1.0742x over previous
//
#include <hip/hip_runtime.h>
#include <hip/hip_bf16.h>
#include <cstdint>
#include <cstddef>

typedef __bf16 bf16_t;
typedef __bf16 bf16x4 __attribute__((ext_vector_type(4)));
typedef __bf16 bf16x8 __attribute__((ext_vector_type(8)));
typedef float f32x4 __attribute__((ext_vector_type(4)));
typedef float f32x16 __attribute__((ext_vector_type(16)));
typedef float f32x2 __attribute__((ext_vector_type(2)));
typedef int i32x4 __attribute__((ext_vector_type(4)));
typedef int i32x8 __attribute__((ext_vector_type(8)));

#define NROWS 8192
#define DFEAT 1024
#define BK 32
#define NBLK 64            // NROWS/128
#define TILE_B (128 * BK)  // bf16 elems per staged tile (8 KB)
#define F8TILE 8192        // fp8 bytes per staged 128x64 tile
#define NPAIR 1056         // paired 128x256 score tiles (incl. 32 half-wasted diag rows)

typedef __attribute__((address_space(3))) unsigned int lds_uint;
typedef __attribute__((address_space(1))) const unsigned int glb_uint;

__device__ __forceinline__ float fast_tanh(float x) {
  float e = __expf(2.0f * x);
  return 1.0f - 2.0f * __builtin_amdgcn_rcpf(e + 1.0f);
}

// pack 4 floats -> 4 fp8 e4m3 bytes (OCP, HW cvt)
__device__ __forceinline__ unsigned pack_fp8x4(float a, float b, float c, float d) {
  unsigned v = 0;
  v = __builtin_amdgcn_cvt_pk_fp8_f32(a, b, v, false);
  v = __builtin_amdgcn_cvt_pk_fp8_f32(c, d, v, true);
  return v;
}

__global__ __launch_bounds__(256) void cast_kernel(const float* __restrict__ in,
                                                   bf16_t* __restrict__ out, int n4) {
  int i = blockIdx.x * 256 + threadIdx.x;
  if (i < n4) {
    float4 v = *(const float4*)(in + i * 4);
    bf16x4 o = {(bf16_t)v.x, (bf16_t)v.y, (bf16_t)v.z, (bf16_t)v.w};
    *(bf16x4*)(out + i * 4) = o;
  }
}

// Async-stage a 128x32 bf16 tile into contiguous LDS [128][32] via global_load_lds w16.
// (4-wave / 256-thread variant)
__device__ __forceinline__ void stage_async(const bf16_t* __restrict__ g, int ld,
                                            int row0, int k0, bf16_t* lds,
                                            int wave, int lane) {
#pragma unroll
  for (int t = 0; t < 2; ++t) {
    const int rb = (t * 4 + wave) * 16;
    const bf16_t* gp = g + (size_t)(row0 + rb + (lane >> 2)) * ld + (k0 + (lane & 3) * 8);
    __builtin_amdgcn_global_load_lds((glb_uint*)gp, (lds_uint*)(lds + rb * BK), 16, 0, 0);
  }
}

// Async-stage a 128x64 fp8 tile into contiguous LDS [128][64B] (row stride 64B).
__device__ __forceinline__ void stage_f8(const uint8_t* __restrict__ g, int ld,
                                         int row0, int k0, uint8_t* lds,
                                         int wave, int lane) {
#pragma unroll
  for (int t = 0; t < 2; ++t) {
    const int rb = (t * 4 + wave) * 16;
    const uint8_t* gp = g + (size_t)(row0 + rb + (lane >> 2)) * ld + (k0 + (lane & 3) * 16);
    __builtin_amdgcn_global_load_lds((glb_uint*)gp, (lds_uint*)(lds + rb * 64), 16, 0, 0);
  }
}

// h = x @ W^T + b, bf16, double-buffered; writes h (bf16, for scores) AND
// hT (fp8 e4m3, consumed only by the MX-fp8 pv kernel).
__global__ __launch_bounds__(256) void gemm1_kernel(const bf16_t* __restrict__ xb,
                                                    const bf16_t* __restrict__ Wb,
                                                    const float* __restrict__ bias,
                                                    bf16_t* __restrict__ hout,
                                                    uint8_t* __restrict__ hT8) {
  __shared__ __align__(16) bf16_t smem[4 * TILE_B];
  const int tid = threadIdx.x;
  const int wave = tid >> 6, lane = tid & 63;
  const int wm = wave >> 1, wn = wave & 1;
  const int l15 = lane & 15, quad = lane >> 4;
  const int m0 = blockIdx.x * 128, n0 = blockIdx.y * 128;
  f32x4 acc[4][4] = {};
  const int NIT = DFEAT / BK;
  stage_async(xb, DFEAT, m0, 0, smem, wave, lane);
  stage_async(Wb, DFEAT, n0, 0, smem + TILE_B, wave, lane);
  __syncthreads();
  for (int it = 0; it < NIT; ++it) {
    bf16_t* lA = smem + (it & 1) * 2 * TILE_B;
    bf16_t* lB = lA + TILE_B;
    if (it + 1 < NIT) {
      bf16_t* nA = smem + ((it + 1) & 1) * 2 * TILE_B;
      stage_async(xb, DFEAT, m0, (it + 1) * BK, nA, wave, lane);
      stage_async(Wb, DFEAT, n0, (it + 1) * BK, nA + TILE_B, wave, lane);
    }
    bf16x8 a[4], b[4];
#pragma unroll
    for (int f = 0; f < 4; ++f) {
      a[f] = *(const bf16x8*)(lA + (wm * 64 + f * 16 + l15) * BK + quad * 8);
      b[f] = *(const bf16x8*)(lB + (wn * 64 + f * 16 + l15) * BK + quad * 8);
    }
#pragma unroll
    for (int i = 0; i < 4; ++i)
#pragma unroll
      for (int j = 0; j < 4; ++j)
        acc[i][j] = __builtin_amdgcn_mfma_f32_16x16x32_bf16(a[i], b[j], acc[i][j], 0, 0, 0);
    __syncthreads();
  }
#pragma unroll
  for (int i = 0; i < 4; ++i) {
    int rbase = m0 + wm * 64 + i * 16 + quad * 4;
#pragma unroll
    for (int j = 0; j < 4; ++j) {
      int col = n0 + wn * 64 + j * 16 + l15;
      float bv = bias[col];
      float hv[4];
#pragma unroll
      for (int r = 0; r < 4; ++r) hv[r] = acc[i][j][r] + bv;
#pragma unroll
      for (int r = 0; r < 4; ++r)
        hout[(size_t)(rbase + r) * DFEAT + col] = (bf16_t)hv[r];
      *(unsigned*)(hT8 + (size_t)col * NROWS + rbase) =
          pack_fp8x4(hv[0], hv[1], hv[2], hv[3]);  // fused transpose, fp8
    }
  }
}

// Symmetric scores, paired 128x256 tiles (512 threads, 8 waves as 2x4 of 64x64).
// Block (bm, p) covers subtiles (bm, 2p) and (bm, 2p+1) with bm <= 2p+1;
// the left subtile is lower-triangle (skipped via predicates) only when
// bm == 2p+1 (32 of 1056 blocks, 1.5% waste). Single-buffered staging
// (dbuf measured-regressive twice), XCD-banded ids. P = exp(tanh(h h^T)) in
// fp8 e4m3; row+col sums from quantized values.
__global__ __launch_bounds__(512) void scores_sym_kernel(const bf16_t* __restrict__ h,
                                                         uint8_t* __restrict__ P,
                                                         float* __restrict__ lsum) {
  __shared__ __align__(16) char smem[256 * 144];  // 24 KB staging / 36.9 KB mirror overlay
  bf16_t* lA = (bf16_t*)smem;                 // [128][32]
  bf16_t* lB = (bf16_t*)smem + 128 * BK;      // [256][32]
  uint8_t (*mir)[144] = (uint8_t(*)[144])smem;  // [256][144] fp8

  int t = (int)(blockIdx.x & 7) * (NPAIR / 8) + (int)(blockIdx.x >> 3);  // XCD banding
  int bm = 0;
  while (t >= 32 - (bm >> 1)) { t -= 32 - (bm >> 1); ++bm; }
  const int p = (bm >> 1) + t;
  const int m0 = bm * 128, n0 = p * 256;
  const bool left_store   = (bm <= 2 * p);   // left subtile upper-or-diagonal
  const bool left_mirror  = (bm <  2 * p);   // strictly upper
  const bool right_mirror = left_store;      // bm < 2p+1  <=>  bm <= 2p

  const int tid = threadIdx.x;
  const int wave = tid >> 6, lane = tid & 63;
  const int wm = wave >> 2, wn = wave & 3;   // 2 x 4 wave grid over 128 x 256
  const int l15 = lane & 15, quad = lane >> 4;

  f32x4 acc[4][4] = {};
  for (int k0 = 0; k0 < DFEAT; k0 += BK) {
    __syncthreads();
    {  // stage A 128x32: 1 issue/wave (8 waves x 16 rows)
      const int rbA = wave * 16;
      const bf16_t* gp = h + (size_t)(m0 + rbA + (lane >> 2)) * DFEAT + (k0 + (lane & 3) * 8);
      __builtin_amdgcn_global_load_lds((glb_uint*)gp, (lds_uint*)(lA + rbA * BK), 16, 0, 0);
    }
#pragma unroll
    for (int t2 = 0; t2 < 2; ++t2) {  // stage B 256x32: 2 issues/wave
      const int rbB = (t2 * 8 + wave) * 16;
      const bf16_t* gp = h + (size_t)(n0 + rbB + (lane >> 2)) * DFEAT + (k0 + (lane & 3) * 8);
      __builtin_amdgcn_global_load_lds((glb_uint*)gp, (lds_uint*)(lB + rbB * BK), 16, 0, 0);
    }
    __syncthreads();
    bf16x8 a[4], b[4];
#pragma unroll
    for (int f = 0; f < 4; ++f) {
      a[f] = *(const bf16x8*)(lA + (wm * 64 + f * 16 + l15) * BK + quad * 8);
      b[f] = *(const bf16x8*)(lB + (wn * 64 + f * 16 + l15) * BK + quad * 8);
    }
#pragma unroll
    for (int i = 0; i < 4; ++i)
#pragma unroll
      for (int j = 0; j < 4; ++j)
        acc[i][j] = __builtin_amdgcn_mfma_f32_16x16x32_bf16(a[i], b[j], acc[i][j], 0, 0, 0);
  }
  __syncthreads();  // staging reads done; smem now free for mirror tile

  const bool do_store  = (wn < 2) ? left_store  : true;
  const bool count_cs  = (wn < 2) ? left_mirror : right_mirror;

  float rs[4][4];
  float cs[4];
#pragma unroll
  for (int i = 0; i < 4; ++i)
#pragma unroll
    for (int r = 0; r < 4; ++r) rs[i][r] = 0.f;
#pragma unroll
  for (int j = 0; j < 4; ++j) cs[j] = 0.f;

#pragma unroll
  for (int i = 0; i < 4; ++i) {
    const int rl_loc = wm * 64 + i * 16 + quad * 4;
    const int rbase = m0 + rl_loc;
#pragma unroll
    for (int j = 0; j < 4; ++j) {
      const int cl_loc = wn * 64 + j * 16 + l15;   // 0..255 within pair
      const int col = n0 + cl_loc;
      float pp[4];
#pragma unroll
      for (int r = 0; r < 4; ++r) pp[r] = __expf(fast_tanh(acc[i][j][r]));
      unsigned packed = pack_fp8x4(pp[0], pp[1], pp[2], pp[3]);
      // dequantize for sums so the softmax denominator matches stored P
      f32x2 d0 = __builtin_amdgcn_cvt_pk_f32_fp8(packed, false);
      f32x2 d1 = __builtin_amdgcn_cvt_pk_f32_fp8(packed, true);
      float q[4] = {d0.x, d0.y, d1.x, d1.y};
      if (do_store) {
#pragma unroll
        for (int r = 0; r < 4; ++r) {
          rs[i][r] += q[r];
          cs[j] += q[r];
          P[(size_t)(rbase + r) * NROWS + col] = (uint8_t)(packed >> (8 * r));
        }
        if (count_cs) *(unsigned*)&mir[cl_loc][rl_loc] = packed;
      }
    }
  }

  // row-sum reduce across the 16 l15 lanes (same rows); each wave adds its own
  // partial (do_store already zeroed skipped halves since rs stays 0)
#pragma unroll
  for (int off = 1; off < 16; off <<= 1)
#pragma unroll
    for (int i = 0; i < 4; ++i)
#pragma unroll
      for (int r = 0; r < 4; ++r) rs[i][r] += __shfl_xor(rs[i][r], off, 64);
  if (l15 == 0 && do_store) {
#pragma unroll
    for (int i = 0; i < 4; ++i) {
      int rbase = m0 + wm * 64 + i * 16 + quad * 4;
#pragma unroll
      for (int r = 0; r < 4; ++r) atomicAdd(&lsum[rbase + r], rs[i][r]);
    }
  }

  // col-sum reduce across the 4 quads (same col), only for mirrored halves
#pragma unroll
  for (int off = 16; off < 64; off <<= 1)
#pragma unroll
    for (int j = 0; j < 4; ++j) cs[j] += __shfl_xor(cs[j], off, 64);
  if (quad == 0 && count_cs) {
#pragma unroll
    for (int j = 0; j < 4; ++j)
      atomicAdd(&lsum[n0 + wn * 64 + j * 16 + l15], cs[j]);
  }

  // mirror write-out: P[n0 + c][m0 .. m0+127] for mirrored halves
  __syncthreads();
#pragma unroll
  for (int it2 = 0; it2 < 4; ++it2) {
    int q2 = tid + it2 * 512;          // 0..2047
    int c = q2 >> 3, r0 = (q2 & 7) * 16;
    bool dom = (c < 128) ? left_mirror : right_mirror;
    if (dom) {
      uint4 v = *(const uint4*)(&mir[c][r0]);
      *(uint4*)(P + (size_t)(n0 + c) * NROWS + m0 + r0) = v;
    }
  }
}

// out = tanh((P @ h) / l): MX-fp8 (e4m3) MFMA with unity scales, K=64/iter,
// double-buffered staging. Grid (x=m=64, y=n=8) keeps same-m0 blocks on one
// XCD -> P strip L2-resident.
__global__ __launch_bounds__(256) void pv_kernel(const uint8_t* __restrict__ P,
                                                 const uint8_t* __restrict__ hT8,
                                                 const float* __restrict__ lsum,
                                                 float* __restrict__ out) {
  __shared__ __align__(16) uint8_t smem[4 * F8TILE];  // 2 phases x (A 8KB + B 8KB)
  const int tid = threadIdx.x;
  const int wave = tid >> 6, lane = tid & 63;
  const int wm = wave >> 1, wn = wave & 1;
  const int l31 = lane & 31, khalf = lane >> 5;
  const int m0 = blockIdx.x * 128, n0 = blockIdx.y * 128;
  f32x16 acc[2][2] = {};
  const int NIT = NROWS / 64;
  stage_f8(P, NROWS, m0, 0, smem, wave, lane);
  stage_f8(hT8, NROWS, n0, 0, smem + F8TILE, wave, lane);
  __syncthreads();
  for (int it = 0; it < NIT; ++it) {
    uint8_t* lA = smem + (it & 1) * 2 * F8TILE;
    uint8_t* lB = lA + F8TILE;
    if (it + 1 < NIT) {
      uint8_t* nA = smem + ((it + 1) & 1) * 2 * F8TILE;
      stage_f8(P, NROWS, m0, (it + 1) * 64, nA, wave, lane);
      stage_f8(hT8, NROWS, n0, (it + 1) * 64, nA + F8TILE, wave, lane);
    }
    i32x8 a[2], b[2];
#pragma unroll
    for (int f = 0; f < 2; ++f) {
      {
        int off = (wm * 64 + f * 32 + l31) * 64 + khalf * 32;
        i32x4 lo = *(const i32x4*)(lA + off);
        i32x4 hi = *(const i32x4*)(lA + off + 16);
        a[f] = i32x8{lo[0], lo[1], lo[2], lo[3], hi[0], hi[1], hi[2], hi[3]};
      }
      {
        int off = (wn * 64 + f * 32 + l31) * 64 + khalf * 32;
        i32x4 lo = *(const i32x4*)(lB + off);
        i32x4 hi = *(const i32x4*)(lB + off + 16);
        b[f] = i32x8{lo[0], lo[1], lo[2], lo[3], hi[0], hi[1], hi[2], hi[3]};
      }
    }
#pragma unroll
    for (int bi = 0; bi < 2; ++bi)
#pragma unroll
      for (int bj = 0; bj < 2; ++bj)
        acc[bi][bj] = __builtin_amdgcn_mfma_scale_f32_32x32x64_f8f6f4(
            a[bi], b[bj], acc[bi][bj], 0, 0, 0, 0x7F7F7F7F, 0, 0x7F7F7F7F);
    __syncthreads();
  }
  // C/D 32x32: col = lane&31, row = (reg&3) + 8*(reg>>2) + 4*(lane>>5)
#pragma unroll
  for (int bi = 0; bi < 2; ++bi)
#pragma unroll
    for (int bj = 0; bj < 2; ++bj) {
      int cbase = n0 + wn * 64 + bj * 32 + l31;
#pragma unroll
      for (int reg = 0; reg < 16; ++reg) {
        int row = m0 + wm * 64 + bi * 32 + (reg & 3) + 8 * (reg >> 2) + 4 * khalf;
        float rl = __builtin_amdgcn_rcpf(lsum[row]);
        out[(size_t)row * DFEAT + cbase] = fast_tanh(acc[bi][bj][reg] * rl);
      }
    }
}

extern "C" void kernel_launch(void* const* d_in, const int* in_sizes, int n_in,
                              void* d_out, int out_size, void* d_ws, size_t ws_size,
                              hipStream_t stream) {
  const float* x = (const float*)d_in[0];
  const float* W = (const float*)d_in[1];
  const float* bias = (const float*)d_in[2];
  float* out = (float*)d_out;

  bf16_t* xb = (bf16_t*)d_ws;                        // 16 MB
  bf16_t* Wb = xb + (size_t)NROWS * DFEAT;           // 2 MB
  bf16_t* h  = Wb + (size_t)DFEAT * DFEAT;           // 16 MB
  uint8_t* hT8 = (uint8_t*)(h + (size_t)NROWS * DFEAT);  // 8 MB (fp8)
  float* lsum = (float*)(hT8 + (size_t)DFEAT * NROWS);
  uint8_t* P = (uint8_t*)(lsum + NROWS);             // 67 MB (fp8)

  cast_kernel<<<(NROWS * DFEAT / 4) / 256, 256, 0, stream>>>(x, xb, NROWS * DFEAT / 4);
  cast_kernel<<<(DFEAT * DFEAT / 4) / 256, 256, 0, stream>>>(W, Wb, DFEAT * DFEAT / 4);
  gemm1_kernel<<<dim3(NROWS / 128, DFEAT / 128), 256, 0, stream>>>(xb, Wb, bias, h, hT8);
  hipMemsetAsync(lsum, 0, NROWS * sizeof(float), stream);
  scores_sym_kernel<<<NPAIR, 512, 0, stream>>>(h, P, lsum);
  pv_kernel<<<dim3(NROWS / 128, DFEAT / 128), 256, 0, stream>>>(P, hT8, lsum, out);
}

// Round 12
// 292.770 us; speedup vs baseline: 1.1916x; 1.1093x over previous
//
#include <hip/hip_runtime.h>
#include <hip/hip_bf16.h>
#include <cstdint>
#include <cstddef>

typedef __bf16 bf16_t;
typedef __bf16 bf16x4 __attribute__((ext_vector_type(4)));
typedef __bf16 bf16x8 __attribute__((ext_vector_type(8)));
typedef float f32x4 __attribute__((ext_vector_type(4)));
typedef float f32x16 __attribute__((ext_vector_type(16)));
typedef float f32x2 __attribute__((ext_vector_type(2)));
typedef int i32x4 __attribute__((ext_vector_type(4)));
typedef int i32x8 __attribute__((ext_vector_type(8)));

#define NROWS 8192
#define DFEAT 1024
#define BK 32
#define NBLK 64            // NROWS/128
#define TILE_B (128 * BK)  // bf16 elems per staged tile (8 KB)
#define F8TILE 8192        // fp8 bytes per staged 128x64 tile
#define NTRI (NBLK * (NBLK + 1) / 2)  // 2080 triangular tiles

typedef __attribute__((address_space(3))) unsigned int lds_uint;
typedef __attribute__((address_space(1))) const unsigned int glb_uint;

__device__ __forceinline__ float fast_tanh(float x) {
  float e = __expf(2.0f * x);
  return 1.0f - 2.0f * __builtin_amdgcn_rcpf(e + 1.0f);
}

// pack 4 floats -> 4 fp8 e4m3 bytes (OCP, HW cvt)
__device__ __forceinline__ unsigned pack_fp8x4(float a, float b, float c, float d) {
  unsigned v = 0;
  v = __builtin_amdgcn_cvt_pk_fp8_f32(a, b, v, false);
  v = __builtin_amdgcn_cvt_pk_fp8_f32(c, d, v, true);
  return v;
}

__global__ __launch_bounds__(256) void cast_kernel(const float* __restrict__ in,
                                                   bf16_t* __restrict__ out, int n4) {
  int i = blockIdx.x * 256 + threadIdx.x;
  if (i < n4) {
    float4 v = *(const float4*)(in + i * 4);
    bf16x4 o = {(bf16_t)v.x, (bf16_t)v.y, (bf16_t)v.z, (bf16_t)v.w};
    *(bf16x4*)(out + i * 4) = o;
  }
}

// Async-stage a 128x32 bf16 tile into contiguous LDS [128][32] via global_load_lds w16.
__device__ __forceinline__ void stage_async(const bf16_t* __restrict__ g, int ld,
                                            int row0, int k0, bf16_t* lds,
                                            int wave, int lane) {
#pragma unroll
  for (int t = 0; t < 2; ++t) {
    const int rb = (t * 4 + wave) * 16;
    const bf16_t* gp = g + (size_t)(row0 + rb + (lane >> 2)) * ld + (k0 + (lane & 3) * 8);
    __builtin_amdgcn_global_load_lds((glb_uint*)gp, (lds_uint*)(lds + rb * BK), 16, 0, 0);
  }
}

// Async-stage a 128x64 fp8 tile into contiguous LDS [128][64B] (row stride 64B).
__device__ __forceinline__ void stage_f8(const uint8_t* __restrict__ g, int ld,
                                         int row0, int k0, uint8_t* lds,
                                         int wave, int lane) {
#pragma unroll
  for (int t = 0; t < 2; ++t) {
    const int rb = (t * 4 + wave) * 16;
    const uint8_t* gp = g + (size_t)(row0 + rb + (lane >> 2)) * ld + (k0 + (lane & 3) * 16);
    __builtin_amdgcn_global_load_lds((glb_uint*)gp, (lds_uint*)(lds + rb * 64), 16, 0, 0);
  }
}

// h = x @ W^T + b, bf16, double-buffered; writes h (bf16, for scores) AND
// hT (fp8 e4m3, consumed only by the MX-fp8 pv kernel).
__global__ __launch_bounds__(256) void gemm1_kernel(const bf16_t* __restrict__ xb,
                                                    const bf16_t* __restrict__ Wb,
                                                    const float* __restrict__ bias,
                                                    bf16_t* __restrict__ hout,
                                                    uint8_t* __restrict__ hT8) {
  __shared__ __align__(16) bf16_t smem[4 * TILE_B];
  const int tid = threadIdx.x;
  const int wave = tid >> 6, lane = tid & 63;
  const int wm = wave >> 1, wn = wave & 1;
  const int l15 = lane & 15, quad = lane >> 4;
  const int m0 = blockIdx.x * 128, n0 = blockIdx.y * 128;
  f32x4 acc[4][4] = {};
  const int NIT = DFEAT / BK;
  stage_async(xb, DFEAT, m0, 0, smem, wave, lane);
  stage_async(Wb, DFEAT, n0, 0, smem + TILE_B, wave, lane);
  __syncthreads();
  for (int it = 0; it < NIT; ++it) {
    bf16_t* lA = smem + (it & 1) * 2 * TILE_B;
    bf16_t* lB = lA + TILE_B;
    if (it + 1 < NIT) {
      bf16_t* nA = smem + ((it + 1) & 1) * 2 * TILE_B;
      stage_async(xb, DFEAT, m0, (it + 1) * BK, nA, wave, lane);
      stage_async(Wb, DFEAT, n0, (it + 1) * BK, nA + TILE_B, wave, lane);
    }
    bf16x8 a[4], b[4];
#pragma unroll
    for (int f = 0; f < 4; ++f) {
      a[f] = *(const bf16x8*)(lA + (wm * 64 + f * 16 + l15) * BK + quad * 8);
      b[f] = *(const bf16x8*)(lB + (wn * 64 + f * 16 + l15) * BK + quad * 8);
    }
#pragma unroll
    for (int i = 0; i < 4; ++i)
#pragma unroll
      for (int j = 0; j < 4; ++j)
        acc[i][j] = __builtin_amdgcn_mfma_f32_16x16x32_bf16(a[i], b[j], acc[i][j], 0, 0, 0);
    __syncthreads();
  }
#pragma unroll
  for (int i = 0; i < 4; ++i) {
    int rbase = m0 + wm * 64 + i * 16 + quad * 4;
#pragma unroll
    for (int j = 0; j < 4; ++j) {
      int col = n0 + wn * 64 + j * 16 + l15;
      float bv = bias[col];
      float hv[4];
#pragma unroll
      for (int r = 0; r < 4; ++r) hv[r] = acc[i][j][r] + bv;
#pragma unroll
      for (int r = 0; r < 4; ++r)
        hout[(size_t)(rbase + r) * DFEAT + col] = (bf16_t)hv[r];
      *(unsigned*)(hT8 + (size_t)col * NROWS + rbase) =
          pack_fp8x4(hv[0], hv[1], hv[2], hv[3]);  // fused transpose, fp8
    }
  }
}

// Symmetric scores (round-9 verified body; ONLY change: supertile-scheduled
// tile decode). The 64x64 tile triangle is partitioned into 8x8-tile
// supertiles (1024-row bands; A+B footprint 4 MB = one XCD L2). Each
// supertile is bound to one XCD (id%8): XCD k runs its diagonal supertile
// (36 tiles) + 3 off-diag (64 each) + half of a shared off-diag (32) = 260
// slots. Co-resident blocks per XCD then share one supertile's strips ->
// staged reads served from L2 instead of L3.
__global__ __launch_bounds__(256) void scores_sym_kernel(const bf16_t* __restrict__ h,
                                                         uint8_t* __restrict__ P,
                                                         float* __restrict__ lsum) {
  __shared__ __align__(16) char smem[128 * 144];  // staging 16KB / mirror 18KB overlay
  bf16_t* lA = (bf16_t*)smem;
  bf16_t* lB = (bf16_t*)(smem + 128 * BK * 2);
  uint8_t (*mir)[144] = (uint8_t(*)[144])smem;

  // supertile decode: id -> (bm, bn), bm <= bn
  const int k = (int)blockIdx.x & 7;   // XCD
  const int s = (int)blockIdx.x >> 3;  // slot 0..259
  int I, J, r, c;
  if (s < 36) {               // diagonal supertile (k,k): 36 upper-tri tiles
    I = J = k;
    int tt = s; r = 0;
    while (tt >= 8 - r) { tt -= 8 - r; ++r; }
    c = r + tt;
  } else {
    int e, t;
    if (s < 228) { e = 3 * k + (s - 36) / 64; t = (s - 36) & 63; }  // 3 full off-diag
    else { e = 24 + (k >> 1); t = ((k & 1) << 5) + (s - 228); }     // shared half
    int ee = e; I = 0;
    while (ee >= 7 - I) { ee -= 7 - I; ++I; }  // off-diag supertile e -> (I,J), I<J
    J = I + 1 + ee;
    r = t >> 3; c = t & 7;
  }
  const int bm = I * 8 + r, bn = J * 8 + c;
  const bool offdiag = (bm != bn);
  const int m0 = bm * 128, n0 = bn * 128;

  const int tid = threadIdx.x;
  const int wave = tid >> 6, lane = tid & 63;
  const int wm = wave >> 1, wn = wave & 1;
  const int l15 = lane & 15, quad = lane >> 4;

  f32x4 acc[4][4] = {};
  for (int k0 = 0; k0 < DFEAT; k0 += BK) {
    __syncthreads();
    stage_async(h, DFEAT, m0, k0, lA, wave, lane);
    stage_async(h, DFEAT, n0, k0, lB, wave, lane);
    __syncthreads();
    bf16x8 a[4], b[4];
#pragma unroll
    for (int f = 0; f < 4; ++f) {
      a[f] = *(const bf16x8*)(lA + (wm * 64 + f * 16 + l15) * BK + quad * 8);
      b[f] = *(const bf16x8*)(lB + (wn * 64 + f * 16 + l15) * BK + quad * 8);
    }
#pragma unroll
    for (int i = 0; i < 4; ++i)
#pragma unroll
      for (int j = 0; j < 4; ++j)
        acc[i][j] = __builtin_amdgcn_mfma_f32_16x16x32_bf16(a[i], b[j], acc[i][j], 0, 0, 0);
  }
  __syncthreads();  // staging reads done; smem now free for mirror tile

  float rs[4][4];
  float cs[4];
#pragma unroll
  for (int i = 0; i < 4; ++i)
#pragma unroll
    for (int r2 = 0; r2 < 4; ++r2) rs[i][r2] = 0.f;
#pragma unroll
  for (int j = 0; j < 4; ++j) cs[j] = 0.f;

#pragma unroll
  for (int i = 0; i < 4; ++i) {
    const int rl_loc = wm * 64 + i * 16 + quad * 4;
    const int rbase = m0 + rl_loc;
#pragma unroll
    for (int j = 0; j < 4; ++j) {
      const int cl_loc = wn * 64 + j * 16 + l15;
      const int col = n0 + cl_loc;
      float p[4];
#pragma unroll
      for (int r2 = 0; r2 < 4; ++r2) p[r2] = __expf(fast_tanh(acc[i][j][r2]));
      unsigned packed = pack_fp8x4(p[0], p[1], p[2], p[3]);
      // dequantize for sums so the softmax denominator matches stored P
      f32x2 d0 = __builtin_amdgcn_cvt_pk_f32_fp8(packed, false);
      f32x2 d1 = __builtin_amdgcn_cvt_pk_f32_fp8(packed, true);
      float q[4] = {d0.x, d0.y, d1.x, d1.y};
#pragma unroll
      for (int r2 = 0; r2 < 4; ++r2) {
        rs[i][r2] += q[r2];
        cs[j] += q[r2];
        P[(size_t)(rbase + r2) * NROWS + col] = (uint8_t)(packed >> (8 * r2));
      }
      if (offdiag) *(unsigned*)&mir[cl_loc][rl_loc] = packed;
    }
  }

#pragma unroll
  for (int off = 1; off < 16; off <<= 1)
#pragma unroll
    for (int i = 0; i < 4; ++i)
#pragma unroll
      for (int r2 = 0; r2 < 4; ++r2) rs[i][r2] += __shfl_xor(rs[i][r2], off, 64);
  if (l15 == 0) {
#pragma unroll
    for (int i = 0; i < 4; ++i) {
      int rbase = m0 + wm * 64 + i * 16 + quad * 4;
#pragma unroll
      for (int r2 = 0; r2 < 4; ++r2) atomicAdd(&lsum[rbase + r2], rs[i][r2]);
    }
  }

  if (offdiag) {
#pragma unroll
    for (int off = 16; off < 64; off <<= 1)
#pragma unroll
      for (int j = 0; j < 4; ++j) cs[j] += __shfl_xor(cs[j], off, 64);
    if (quad == 0) {
#pragma unroll
      for (int j = 0; j < 4; ++j)
        atomicAdd(&lsum[n0 + wn * 64 + j * 16 + l15], cs[j]);
    }
    __syncthreads();
#pragma unroll
    for (int it = 0; it < 4; ++it) {
      int q2 = tid + it * 256;          // 0..1023
      int c2 = q2 >> 3, r0 = (q2 & 7) * 16;
      uint4 v = *(const uint4*)(&mir[c2][r0]);
      *(uint4*)(P + (size_t)(n0 + c2) * NROWS + m0 + r0) = v;
    }
  }
}

// out = tanh((P @ h) / l): MX-fp8 (e4m3) MFMA with unity scales, K=64/iter,
// double-buffered staging. Grid (x=m=64, y=n=8) keeps same-m0 blocks on one
// XCD -> P strip L2-resident.
__global__ __launch_bounds__(256) void pv_kernel(const uint8_t* __restrict__ P,
                                                 const uint8_t* __restrict__ hT8,
                                                 const float* __restrict__ lsum,
                                                 float* __restrict__ out) {
  __shared__ __align__(16) uint8_t smem[4 * F8TILE];  // 2 phases x (A 8KB + B 8KB)
  const int tid = threadIdx.x;
  const int wave = tid >> 6, lane = tid & 63;
  const int wm = wave >> 1, wn = wave & 1;
  const int l31 = lane & 31, khalf = lane >> 5;
  const int m0 = blockIdx.x * 128, n0 = blockIdx.y * 128;
  f32x16 acc[2][2] = {};
  const int NIT = NROWS / 64;
  stage_f8(P, NROWS, m0, 0, smem, wave, lane);
  stage_f8(hT8, NROWS, n0, 0, smem + F8TILE, wave, lane);
  __syncthreads();
  for (int it = 0; it < NIT; ++it) {
    uint8_t* lA = smem + (it & 1) * 2 * F8TILE;
    uint8_t* lB = lA + F8TILE;
    if (it + 1 < NIT) {
      uint8_t* nA = smem + ((it + 1) & 1) * 2 * F8TILE;
      stage_f8(P, NROWS, m0, (it + 1) * 64, nA, wave, lane);
      stage_f8(hT8, NROWS, n0, (it + 1) * 64, nA + F8TILE, wave, lane);
    }
    i32x8 a[2], b[2];
#pragma unroll
    for (int f = 0; f < 2; ++f) {
      {
        int off = (wm * 64 + f * 32 + l31) * 64 + khalf * 32;
        i32x4 lo = *(const i32x4*)(lA + off);
        i32x4 hi = *(const i32x4*)(lA + off + 16);
        a[f] = i32x8{lo[0], lo[1], lo[2], lo[3], hi[0], hi[1], hi[2], hi[3]};
      }
      {
        int off = (wn * 64 + f * 32 + l31) * 64 + khalf * 32;
        i32x4 lo = *(const i32x4*)(lB + off);
        i32x4 hi = *(const i32x4*)(lB + off + 16);
        b[f] = i32x8{lo[0], lo[1], lo[2], lo[3], hi[0], hi[1], hi[2], hi[3]};
      }
    }
#pragma unroll
    for (int bi = 0; bi < 2; ++bi)
#pragma unroll
      for (int bj = 0; bj < 2; ++bj)
        acc[bi][bj] = __builtin_amdgcn_mfma_scale_f32_32x32x64_f8f6f4(
            a[bi], b[bj], acc[bi][bj], 0, 0, 0, 0x7F7F7F7F, 0, 0x7F7F7F7F);
    __syncthreads();
  }
  // C/D 32x32: col = lane&31, row = (reg&3) + 8*(reg>>2) + 4*(lane>>5)
#pragma unroll
  for (int bi = 0; bi < 2; ++bi)
#pragma unroll
    for (int bj = 0; bj < 2; ++bj) {
      int cbase = n0 + wn * 64 + bj * 32 + l31;
#pragma unroll
      for (int reg = 0; reg < 16; ++reg) {
        int row = m0 + wm * 64 + bi * 32 + (reg & 3) + 8 * (reg >> 2) + 4 * khalf;
        float rl = __builtin_amdgcn_rcpf(lsum[row]);
        out[(size_t)row * DFEAT + cbase] = fast_tanh(acc[bi][bj][reg] * rl);
      }
    }
}

extern "C" void kernel_launch(void* const* d_in, const int* in_sizes, int n_in,
                              void* d_out, int out_size, void* d_ws, size_t ws_size,
                              hipStream_t stream) {
  const float* x = (const float*)d_in[0];
  const float* W = (const float*)d_in[1];
  const float* bias = (const float*)d_in[2];
  float* out = (float*)d_out;

  bf16_t* xb = (bf16_t*)d_ws;                        // 16 MB
  bf16_t* Wb = xb + (size_t)NROWS * DFEAT;           // 2 MB
  bf16_t* h  = Wb + (size_t)DFEAT * DFEAT;           // 16 MB
  uint8_t* hT8 = (uint8_t*)(h + (size_t)NROWS * DFEAT);  // 8 MB (fp8)
  float* lsum = (float*)(hT8 + (size_t)DFEAT * NROWS);
  uint8_t* P = (uint8_t*)(lsum + NROWS);             // 67 MB (fp8)

  cast_kernel<<<(NROWS * DFEAT / 4) / 256, 256, 0, stream>>>(x, xb, NROWS * DFEAT / 4);
  cast_kernel<<<(DFEAT * DFEAT / 4) / 256, 256, 0, stream>>>(W, Wb, DFEAT * DFEAT / 4);
  gemm1_kernel<<<dim3(NROWS / 128, DFEAT / 128), 256, 0, stream>>>(xb, Wb, bias, h, hT8);
  hipMemsetAsync(lsum, 0, NROWS * sizeof(float), stream);
  scores_sym_kernel<<<NTRI, 256, 0, stream>>>(h, P, lsum);
  pv_kernel<<<dim3(NROWS / 128, DFEAT / 128), 256, 0, stream>>>(P, hT8, lsum, out);
}